// Round 11
// baseline (885.368 us; speedup 1.0000x reference)
//
#include <hip/hip_runtime.h>
#include <hip/hip_bf16.h>
#include <cstdint>
#include <cstddef>

#define B_    8
#define L_    256
#define DM_   1024
#define DI_   2048
#define N_    16
#define K_    4
#define NL_   4
#define DTR_  128
#define P_    97
#define XPD_  160   // DTR + 2N
#define CHUNK_ 32
#define NC_   8     // L / CHUNK

typedef __attribute__((ext_vector_type(8))) short short8;
typedef __attribute__((ext_vector_type(4))) float floatx4;

__device__ __forceinline__ void async16(const void* g, void* l)
{
    __builtin_amdgcn_global_load_lds(
        (const __attribute__((address_space(1))) void*)g,
        (__attribute__((address_space(3))) void*)l,
        16, 0, 0);
}

__device__ __forceinline__ float bf2f(__hip_bfloat16 h) { return __bfloat162float(h); }

// ---------------------------------------------------------------------------
// Embedding + layer-0 LayerNorm. One block per (b,l) row.
// ---------------------------------------------------------------------------
__global__ __launch_bounds__(256)
void embed_ln_k(const int* __restrict__ tokens, const float* __restrict__ te,
                const float* __restrict__ pe, const float* __restrict__ lw,
                const float* __restrict__ lb, float* __restrict__ h,
                __hip_bfloat16* __restrict__ xout)
{
    __shared__ float red[8];
    int bl = blockIdx.x;
    int l  = bl & (L_ - 1);
    int tok = tokens[bl];
    int tid = threadIdx.x;
    float4 a = *(const float4*)(te + (size_t)tok * DM_ + tid * 4);
    float4 p = *(const float4*)(pe + (size_t)l * DM_ + tid * 4);
    float4 x = make_float4(a.x + p.x, a.y + p.y, a.z + p.z, a.w + p.w);
    size_t base = (size_t)bl * DM_ + tid * 4;
    *(float4*)(h + base) = x;

    float s  = x.x + x.y + x.z + x.w;
    float s2 = x.x * x.x + x.y * x.y + x.z * x.z + x.w * x.w;
    #pragma unroll
    for (int o = 32; o > 0; o >>= 1) {
        s  += __shfl_down(s, o);
        s2 += __shfl_down(s2, o);
    }
    if ((tid & 63) == 0) { red[tid >> 6] = s; red[4 + (tid >> 6)] = s2; }
    __syncthreads();
    float st  = red[0] + red[1] + red[2] + red[3];
    float s2t = red[4] + red[5] + red[6] + red[7];
    float m   = st * (1.f / DM_);
    float var = s2t * (1.f / DM_) - m * m;
    float rs  = rsqrtf(var + 1e-5f);
    float4 wv = *(const float4*)(lw + tid * 4);
    float4 bv = *(const float4*)(lb + tid * 4);
    union { __hip_bfloat16 h[4]; ushort4 u; } t;
    t.h[0] = __float2bfloat16((x.x - m) * rs * wv.x + bv.x);
    t.h[1] = __float2bfloat16((x.y - m) * rs * wv.y + bv.y);
    t.h[2] = __float2bfloat16((x.z - m) * rs * wv.z + bv.z);
    t.h[3] = __float2bfloat16((x.w - m) * rs * wv.w + bv.w);
    *(ushort4*)(xout + base) = t.u;
}

// ---------------------------------------------------------------------------
// MFMA GEMM, A bf16 + B fp32 (raw weights), BOTH async-staged to LDS.
// BK=64 as two BK=32 images. XOR-swizzled LDS layouts (conflict-free reads):
//   A (bf16, 64B rows, 4 x 16B groups):  lds_kg = g ^ ((row>>1)&3)
//   B (fp32, 128B rows, 8 x 16B groups): lds_kg = g ^ (row&7)
// Staging exploits global_load_lds: per-lane GLOBAL address is free, LDS dst
// is lane-linear — so each slot fetches the global group that belongs there.
// B fragments are converted fp32->bf16 in registers at read time.
// MODE 0: full-K -> bf16 C
// MODE 2: split-K partial -> fp32 Cp[z][M][ldc]
// MODE 3: split-K partial fp32; B global rows clamped to Nb-1 (OOB-safe),
//         epilogue skips cols >= Nb  (xproj: raw 160-row weights)
// MODE 5: full-K, bias+softplus -> bf16 C (dt matmul)
// Kp must be a multiple of 64.
// ---------------------------------------------------------------------------
template<int MODE, int TN>
__global__ __launch_bounds__(256)
void gemm_wsw(const __hip_bfloat16* __restrict__ A, int lda,
              const float* __restrict__ Bw, int ldb,
              void* __restrict__ Cv, int ldc, int Kp, int Nb,
              const float* __restrict__ bias)
{
    constexpr int JW = (TN == 128) ? 4 : 2;
    constexpr int BQ = (TN * 8) / 256;       // B 16B-slots per thread per image
    __shared__ __hip_bfloat16 As[2][128 * 32];
    __shared__ float          Bs[2][TN * 32];
    const int tid  = threadIdx.x;
    const int lane = tid & 63;
    const int wid  = tid >> 6;
    const int wm   = wid >> 1, wn = wid & 1;
    const int mbase = blockIdx.y * 128;
    const int nbase = blockIdx.x * TN;
    const int koff  = (MODE == 2 || MODE == 3) ? blockIdx.z * Kp : 0;

    floatx4 acc[4][JW] = {};

    // A slot map: slot s in {tid, tid+256}: row = s>>2, kg_lds = s&3
    const int ar0 = tid >> 2;
    const int ar1 = ar0 + 64;
    const int akg = tid & 3;
    const size_t aoff0 = (size_t)ar0 * lda * 2 + ((akg ^ ((ar0 >> 1) & 3)) << 4);
    const size_t aoff1 = (size_t)ar1 * lda * 2 + ((akg ^ ((ar1 >> 1) & 3)) << 4);

    // B slot map: slot s = tid + 256q: row = s>>3, kg_lds = s&7
    const int bkg = tid & 7;
    size_t boff[BQ];
    #pragma unroll
    for (int q = 0; q < BQ; ++q) {
        int br = (tid >> 3) + 32 * q;        // local row in tile
        int grow = nbase + br;               // global weight row
        if (MODE == 3 && grow >= Nb) grow = Nb - 1;
        boff[q] = (size_t)grow * ldb * 4 + ((bkg ^ (br & 7)) << 4);
    }

    const int hq = lane >> 4;                // k-quarter 0..3
    const int fr = lane & 15;

    for (int k0 = koff; k0 < koff + Kp; k0 += 64) {
        const char* Ag0 = (const char*)(A + (size_t)mbase * lda + k0);
        const char* Bg0 = (const char*)Bw + (size_t)k0 * 4;
        #pragma unroll
        for (int hh = 0; hh < 2; ++hh) {
            const char* Ag = Ag0 + hh * 64;    // +32 bf16
            const char* Bg = Bg0 + hh * 128;   // +32 fp32
            async16(Ag + aoff0, (char*)As[hh] + tid * 16);
            async16(Ag + aoff1, (char*)As[hh] + (tid + 256) * 16);
            #pragma unroll
            for (int q = 0; q < BQ; ++q)
                async16(Bg + boff[q], (char*)Bs[hh] + (tid + 256 * q) * 16);
        }
        __syncthreads();

        #pragma unroll
        for (int hh = 0; hh < 2; ++hh) {
            short8 af[4], bf[JW];
            #pragma unroll
            for (int i = 0; i < 4; ++i) {
                int m = wm * 64 + i * 16 + fr;
                af[i] = *(const short8*)((const char*)As[hh] + m * 64 +
                                         ((hq ^ ((m >> 1) & 3)) << 4));
            }
            #pragma unroll
            for (int j = 0; j < JW; ++j) {
                int n = wn * (TN / 2) + j * 16 + fr;
                const char* bp = (const char*)(Bs[hh] + n * 32);
                int g0 = hq * 2, g1 = g0 + 1;
                float4 f0 = *(const float4*)(bp + ((g0 ^ (n & 7)) << 4));
                float4 f1 = *(const float4*)(bp + ((g1 ^ (n & 7)) << 4));
                union { __hip_bfloat16 h[8]; short8 u; } tb;
                tb.h[0] = __float2bfloat16(f0.x); tb.h[1] = __float2bfloat16(f0.y);
                tb.h[2] = __float2bfloat16(f0.z); tb.h[3] = __float2bfloat16(f0.w);
                tb.h[4] = __float2bfloat16(f1.x); tb.h[5] = __float2bfloat16(f1.y);
                tb.h[6] = __float2bfloat16(f1.z); tb.h[7] = __float2bfloat16(f1.w);
                bf[j] = tb.u;
            }
            #pragma unroll
            for (int i = 0; i < 4; ++i)
                #pragma unroll
                for (int j = 0; j < JW; ++j)
                    acc[i][j] = __builtin_amdgcn_mfma_f32_16x16x32_bf16(
                        af[i], bf[j], acc[i][j], 0, 0, 0);
        }
        __syncthreads();
    }

    const int cq = lane >> 4;
    float* Cf = (float*)Cv;
    __hip_bfloat16* Ch = (__hip_bfloat16*)Cv;
    size_t zoff = (MODE == 2 || MODE == 3)
                ? (size_t)blockIdx.z * (gridDim.y * 128) * ldc : 0;
    #pragma unroll
    for (int i = 0; i < 4; ++i) {
        #pragma unroll
        for (int j = 0; j < JW; ++j) {
            int col = nbase + wn * (TN / 2) + j * 16 + fr;
            if (MODE == 3 && col >= Nb) continue;
            float bv = (MODE == 5) ? bias[col] : 0.f;
            #pragma unroll
            for (int r = 0; r < 4; ++r) {
                int row = mbase + wm * 64 + i * 16 + cq * 4 + r;
                float v = acc[i][j][r];
                size_t off = zoff + (size_t)row * ldc + col;
                if (MODE == 2 || MODE == 3) {
                    Cf[off] = v;
                } else if (MODE == 5) {
                    v += bv;
                    v = (v > 20.f) ? v : log1pf(__expf(v));
                    Ch[off] = __float2bfloat16(v);
                } else {
                    Ch[off] = __float2bfloat16(v);
                }
            }
        }
    }
}

// ---------------------------------------------------------------------------
// Split-K reduce for xp: emit fp32 xp AND bf16 xp_b
// ---------------------------------------------------------------------------
template<int PARTS>
__global__ __launch_bounds__(256)
void reduce_xp_k(const float* __restrict__ p, float* __restrict__ dst,
                 __hip_bfloat16* __restrict__ dst_b, size_t stride)
{
    size_t i = ((size_t)blockIdx.x * 256 + threadIdx.x) * 4;
    float4 s = *(const float4*)(p + i);
    #pragma unroll
    for (int z = 1; z < PARTS; ++z) {
        float4 v = *(const float4*)(p + z * stride + i);
        s.x += v.x; s.y += v.y; s.z += v.z; s.w += v.w;
    }
    *(float4*)(dst + i) = s;
    union { __hip_bfloat16 h[4]; ushort4 u; } t;
    t.h[0] = __float2bfloat16(s.x);
    t.h[1] = __float2bfloat16(s.y);
    t.h[2] = __float2bfloat16(s.z);
    t.h[3] = __float2bfloat16(s.w);
    *(ushort4*)(dst_b + i) = t.u;
}

// ---------------------------------------------------------------------------
// Fused: h[row] += sum_z part[z][row]; then LayerNorm(h[row]) -> bf16 out.
// ---------------------------------------------------------------------------
template<int PARTS>
__global__ __launch_bounds__(256)
void reduce_ln_k(const float* __restrict__ p, float* __restrict__ h,
                 const float* __restrict__ w, const float* __restrict__ b,
                 __hip_bfloat16* __restrict__ out, size_t stride)
{
    __shared__ float red[8];
    int tid = threadIdx.x;
    size_t base = (size_t)blockIdx.x * DM_ + tid * 4;
    float4 x = *(const float4*)(h + base);
    #pragma unroll
    for (int z = 0; z < PARTS; ++z) {
        float4 v = *(const float4*)(p + z * stride + base);
        x.x += v.x; x.y += v.y; x.z += v.z; x.w += v.w;
    }
    *(float4*)(h + base) = x;

    float s  = x.x + x.y + x.z + x.w;
    float s2 = x.x * x.x + x.y * x.y + x.z * x.z + x.w * x.w;
    #pragma unroll
    for (int o = 32; o > 0; o >>= 1) {
        s  += __shfl_down(s, o);
        s2 += __shfl_down(s2, o);
    }
    if ((tid & 63) == 0) { red[tid >> 6] = s; red[4 + (tid >> 6)] = s2; }
    __syncthreads();
    float st  = red[0] + red[1] + red[2] + red[3];
    float s2t = red[4] + red[5] + red[6] + red[7];
    float m   = st * (1.f / DM_);
    float var = s2t * (1.f / DM_) - m * m;
    float rs  = rsqrtf(var + 1e-5f);
    float4 wv = *(const float4*)(w + tid * 4);
    float4 bv = *(const float4*)(b + tid * 4);
    union { __hip_bfloat16 h[4]; ushort4 u; } t;
    t.h[0] = __float2bfloat16((x.x - m) * rs * wv.x + bv.x);
    t.h[1] = __float2bfloat16((x.y - m) * rs * wv.y + bv.y);
    t.h[2] = __float2bfloat16((x.z - m) * rs * wv.z + bv.z);
    t.h[3] = __float2bfloat16((x.w - m) * rs * wv.w + bv.w);
    *(ushort4*)(out + base) = t.u;
}

// ---------------------------------------------------------------------------
// Causal depthwise conv (K=4) + SiLU; bf16 in/out, 8 channels/thread (16B)
// ---------------------------------------------------------------------------
__global__ __launch_bounds__(256)
void conv_silu(const __hip_bfloat16* __restrict__ xz, const float* __restrict__ cw,
               const float* __restrict__ cb, __hip_bfloat16* __restrict__ xb_b)
{
    int idx = blockIdx.x * 256 + threadIdx.x;    // over B*L*(DI/8)
    int d  = (idx & 255) << 3;
    int bl = idx >> 8;
    int l  = bl & (L_ - 1);
    float4 w[8];
    #pragma unroll
    for (int j = 0; j < 8; ++j) w[j] = *(const float4*)(cw + (d + j) * 4);
    float acc[8];
    {
        float4 b0 = *(const float4*)(cb + d);
        float4 b1 = *(const float4*)(cb + d + 4);
        acc[0] = b0.x; acc[1] = b0.y; acc[2] = b0.z; acc[3] = b0.w;
        acc[4] = b1.x; acc[5] = b1.y; acc[6] = b1.z; acc[7] = b1.w;
    }
    #pragma unroll
    for (int k = 0; k < 4; ++k) {
        int lk = l + k - 3;
        if (lk >= 0) {
            union { short8 u; __hip_bfloat16 h[8]; } xu;
            xu.u = *(const short8*)(xz + (size_t)(bl - l + lk) * (2 * DI_) + d);
            #pragma unroll
            for (int j = 0; j < 8; ++j)
                acc[j] += ((const float*)&w[j])[k] * bf2f(xu.h[j]);
        }
    }
    union { __hip_bfloat16 h[8]; short8 u; } t;
    #pragma unroll
    for (int j = 0; j < 8; ++j) {
        float v = acc[j] / (1.f + __expf(-acc[j]));
        t.h[j] = __float2bfloat16(v);
    }
    *(short8*)(xb_b + (size_t)bl * DI_ + d) = t.u;
}

// ---------------------------------------------------------------------------
// SSM pass1: per-chunk local scan from 0 -> decay product Pc, local state Sc
// ---------------------------------------------------------------------------
__global__ __launch_bounds__(256)
void ssm_pass1(const __hip_bfloat16* __restrict__ xb_b,
               const __hip_bfloat16* __restrict__ dlt_b,
               const float* __restrict__ xp, const float* __restrict__ Alog,
               float* __restrict__ Pc, float* __restrict__ Sc)
{
    int blk = blockIdx.x;
    int dgrp = blk & 7, c = (blk >> 3) & 7, b = blk >> 6;
    int d = (dgrp << 8) + threadIdx.x;
    __shared__ float Bsh[CHUNK_][N_];
    for (int i = threadIdx.x; i < CHUNK_ * N_; i += 256) {
        int t = i >> 4, n = i & 15;
        Bsh[t][n] = xp[(size_t)(b * L_ + c * CHUNK_ + t) * XPD_ + DTR_ + n];
    }
    __syncthreads();
    float a[N_], hn[N_], Pn[N_];
    #pragma unroll
    for (int n = 0; n < N_; ++n) {
        a[n] = -__expf(Alog[d * N_ + n]);
        hn[n] = 0.f; Pn[n] = 1.f;
    }
    for (int t = 0; t < CHUNK_; ++t) {
        size_t off = (size_t)(b * L_ + c * CHUNK_ + t) * DI_ + d;
        float dt = bf2f(dlt_b[off]);
        float xv = bf2f(xb_b[off]);
        float dx = dt * xv;
        #pragma unroll
        for (int n = 0; n < N_; ++n) {
            float dA = __expf(dt * a[n]);
            hn[n] = dA * hn[n] + dx * Bsh[t][n];
            Pn[n] *= dA;
        }
    }
    #pragma unroll
    for (int n = 0; n < N_; ++n) {
        size_t o = ((size_t)((b * NC_ + c) * N_ + n)) * DI_ + d;
        Pc[o] = Pn[n]; Sc[o] = hn[n];
    }
}

// ---------------------------------------------------------------------------
// SSM pass2: prefix over earlier chunks (Pc/Sc L2-hot); re-run chunk;
// y = (C.h + x*D) * silu(z) -> bf16
// ---------------------------------------------------------------------------
__global__ __launch_bounds__(256)
void ssm_pass2(const __hip_bfloat16* __restrict__ xb_b,
               const __hip_bfloat16* __restrict__ dlt_b,
               const float* __restrict__ xp, const float* __restrict__ Alog,
               const float* __restrict__ Dp, const __hip_bfloat16* __restrict__ xz,
               const float* __restrict__ Pc, const float* __restrict__ Sc,
               __hip_bfloat16* __restrict__ yout)
{
    int blk = blockIdx.x;
    int dgrp = blk & 7, c = (blk >> 3) & 7, b = blk >> 6;
    int d = (dgrp << 8) + threadIdx.x;
    __shared__ float Bsh[CHUNK_][N_], Csh[CHUNK_][N_];
    for (int i = threadIdx.x; i < CHUNK_ * 2 * N_; i += 256) {
        int t = i >> 5, j = i & 31;
        float v = xp[(size_t)(b * L_ + c * CHUNK_ + t) * XPD_ + DTR_ + j];
        if (j < 16) Bsh[t][j] = v; else Csh[t][j - 16] = v;
    }
    __syncthreads();
    float a[N_], hn[N_];
    #pragma unroll
    for (int n = 0; n < N_; ++n) {
        a[n] = -__expf(Alog[d * N_ + n]);
        hn[n] = 0.f;
    }
    for (int cp = 0; cp < c; ++cp) {
        #pragma unroll
        for (int n = 0; n < N_; ++n) {
            size_t o = ((size_t)((b * NC_ + cp) * N_ + n)) * DI_ + d;
            hn[n] = Pc[o] * hn[n] + Sc[o];
        }
    }
    float dpv = Dp[d];
    for (int t = 0; t < CHUNK_; ++t) {
        int l = c * CHUNK_ + t;
        size_t off = (size_t)(b * L_ + l) * DI_ + d;
        float dt = bf2f(dlt_b[off]);
        float xv = bf2f(xb_b[off]);
        float dx = dt * xv;
        float yv = 0.f;
        #pragma unroll
        for (int n = 0; n < N_; ++n) {
            float dA = __expf(dt * a[n]);
            hn[n] = dA * hn[n] + dx * Bsh[t][n];
            yv += hn[n] * Csh[t][n];
        }
        yv += xv * dpv;
        float z = bf2f(xz[(size_t)(b * L_ + l) * (2 * DI_) + DI_ + d]);
        yout[off] = __float2bfloat16(yv * z / (1.f + __expf(-z)));
    }
}

// ---------------------------------------------------------------------------
// Fused last-layer part-sum + final LayerNorm + head.
// ---------------------------------------------------------------------------
__global__ __launch_bounds__(256)
void head_ln_k(const float* __restrict__ h, const float* __restrict__ parts,
               size_t pstride,
               const float* __restrict__ fw, const float* __restrict__ fb,
               const float* __restrict__ hw, float* __restrict__ out)
{
    __shared__ float red[4][5];
    int b = blockIdx.x / P_;
    int p = blockIdx.x % P_;
    int tid = threadIdx.x;
    size_t rowoff = ((size_t)(b * L_ + L_ - 1)) * DM_ + tid * 4;
    float4 x  = *(const float4*)(h + rowoff);
    float4 p0 = *(const float4*)(parts + rowoff);
    float4 p1 = *(const float4*)(parts + pstride + rowoff);
    x.x += p0.x + p1.x; x.y += p0.y + p1.y;
    x.z += p0.z + p1.z; x.w += p0.w + p1.w;
    float4 w4 = *(const float4*)(fw + tid * 4);
    float4 b4 = *(const float4*)(fb + tid * 4);
    float4 g4 = *(const float4*)(hw + (size_t)p * DM_ + tid * 4);
    float s  = x.x + x.y + x.z + x.w;
    float s2 = x.x * x.x + x.y * x.y + x.z * x.z + x.w * x.w;
    float t1 = x.x * w4.x * g4.x + x.y * w4.y * g4.y + x.z * w4.z * g4.z + x.w * w4.w * g4.w;
    float t2 = w4.x * g4.x + w4.y * g4.y + w4.z * g4.z + w4.w * g4.w;
    float t3 = b4.x * g4.x + b4.y * g4.y + b4.z * g4.z + b4.w * g4.w;
    #pragma unroll
    for (int o = 32; o > 0; o >>= 1) {
        s  += __shfl_down(s, o);
        s2 += __shfl_down(s2, o);
        t1 += __shfl_down(t1, o);
        t2 += __shfl_down(t2, o);
        t3 += __shfl_down(t3, o);
    }
    if ((tid & 63) == 0) {
        int w = tid >> 6;
        red[w][0] = s; red[w][1] = s2; red[w][2] = t1; red[w][3] = t2; red[w][4] = t3;
    }
    __syncthreads();
    if (tid == 0) {
        float st  = red[0][0] + red[1][0] + red[2][0] + red[3][0];
        float s2t = red[0][1] + red[1][1] + red[2][1] + red[3][1];
        float t1t = red[0][2] + red[1][2] + red[2][2] + red[3][2];
        float t2t = red[0][3] + red[1][3] + red[2][3] + red[3][3];
        float t3t = red[0][4] + red[1][4] + red[2][4] + red[3][4];
        float m   = st * (1.f / DM_);
        float var = s2t * (1.f / DM_) - m * m;
        float rs  = rsqrtf(var + 1e-5f);
        out[blockIdx.x] = rs * (t1t - m * t2t) + t3t;
    }
}

// ---------------------------------------------------------------------------
extern "C" void kernel_launch(void* const* d_in, const int* in_sizes, int n_in,
                              void* d_out, int out_size, void* d_ws, size_t ws_size,
                              hipStream_t stream)
{
    const int*   tokens     = (const int*)  d_in[0];
    const float* tok_emb    = (const float*)d_in[1];
    const float* pos_emb    = (const float*)d_in[2];
    const float* ln_w       = (const float*)d_in[3];
    const float* ln_b       = (const float*)d_in[4];
    const float* in_proj_w  = (const float*)d_in[5];
    const float* conv_w     = (const float*)d_in[6];
    const float* conv_b     = (const float*)d_in[7];
    const float* xproj_w    = (const float*)d_in[8];
    const float* dt_w       = (const float*)d_in[9];
    const float* dt_b       = (const float*)d_in[10];
    const float* A_log      = (const float*)d_in[11];
    const float* D_param    = (const float*)d_in[12];
    const float* out_proj_w = (const float*)d_in[13];
    const float* fnorm_w    = (const float*)d_in[14];
    const float* fnorm_b    = (const float*)d_in[15];
    const float* head_w     = (const float*)d_in[16];
    float* out = (float*)d_out;
    float* ws  = (float*)d_ws;

    // fp32 workspace (floats)
    float* h      = ws;                   // B*L*DM    = 2,097,152
    float* xp     = h    + 2097152;       // B*L*XPD   =   327,680
    float* Pc     = xp   + 327680;        // B*NC*N*DI = 2,097,152
    float* Sc     = Pc   + 2097152;       // 2,097,152
    float* part_h = Sc   + 2097152;       // 2 x B*L*DM = 4,194,304
    // bf16 workspace
    __hip_bfloat16* bfb = (__hip_bfloat16*)(part_h + 4194304);
    __hip_bfloat16* xz_b  = bfb;                 // B*L*2DI = 8,388,608 el
    __hip_bfloat16* xln_b = xz_b  + 8388608;     // B*L*DM  = 2,097,152 el
    __hip_bfloat16* y_b   = xln_b + 2097152;     // B*L*DI  = 4,194,304 el
    __hip_bfloat16* xb_b  = y_b   + 4194304;     // B*L*DI  = 4,194,304 el
    __hip_bfloat16* dlt_b = xb_b  + 4194304;     // B*L*DI  = 4,194,304 el
    __hip_bfloat16* xp_b  = dlt_b + 4194304;     // B*L*XPD =   327,680 el
    // split-K partials for xproj alias Pc+Sc (dead until ssm_pass1)
    float* part_xp = Pc;   // 8 x 2048 x 160 = 2,621,440 fl <= 4,194,304 fl

    // ---- embedding + layer-0 LN
    embed_ln_k<<<B_ * L_, 256, 0, stream>>>(tokens, tok_emb, pos_emb,
                                            ln_w, ln_b, h, xln_b);

    for (int li = 0; li < NL_; ++li) {
        // xz = x @ in_proj_w^T  (2048 x 4096, K=1024) -> bf16 [TN=64, BK=64]
        gemm_wsw<0, 64><<<dim3(2 * DI_ / 64, B_ * L_ / 128), 256, 0, stream>>>(
            xln_b, DM_, in_proj_w + (size_t)li * 2 * DI_ * DM_, DM_,
            xz_b, 2 * DI_, DM_, 0, nullptr);

        // x_branch = silu(conv(xz[...,:DI]))  -> bf16 (8 ch/thread)
        conv_silu<<<B_ * L_ * DI_ / 8 / 256, 256, 0, stream>>>(
            xz_b, conv_w + li * DI_ * K_, conv_b + li * DI_, xb_b);

        // xp = x_branch @ xproj_w^T  (2048 x 160, K=2048) [TN=128 splitK-8]
        gemm_wsw<3, 128><<<dim3(2, B_ * L_ / 128, 8), 256, 0, stream>>>(
            xb_b, DI_, xproj_w + (size_t)li * XPD_ * DI_, DI_,
            part_xp, XPD_, DI_ / 8, XPD_, nullptr);
        reduce_xp_k<8><<<B_ * L_ * XPD_ / 1024, 256, 0, stream>>>(
            part_xp, xp, xp_b, (size_t)B_ * L_ * XPD_);

        // delta = softplus(dt_r @ dt_w^T + dt_b) (2048x2048, K=128) [TN=64]
        gemm_wsw<5, 64><<<dim3(DI_ / 64, B_ * L_ / 128), 256, 0, stream>>>(
            xp_b, XPD_, dt_w + (size_t)li * DI_ * DTR_, DTR_,
            dlt_b, DI_, DTR_, 0, dt_b + li * DI_);

        // chunked selective scan
        ssm_pass1<<<B_ * NC_ * (DI_ / 256), 256, 0, stream>>>(
            xb_b, dlt_b, xp, A_log + li * DI_ * N_, Pc, Sc);
        ssm_pass2<<<B_ * NC_ * (DI_ / 256), 256, 0, stream>>>(
            xb_b, dlt_b, xp, A_log + li * DI_ * N_, D_param + li * DI_,
            xz_b, Pc, Sc, y_b);

        // h += y @ out_proj_w^T  (2048 x 1024, K=2048) [TN=64 splitK-2]
        gemm_wsw<2, 64><<<dim3(DM_ / 64, B_ * L_ / 128, 2), 256, 0, stream>>>(
            y_b, DI_, out_proj_w + (size_t)li * DM_ * DI_, DI_,
            part_h, DM_, DI_ / 2, 0, nullptr);

        if (li < NL_ - 1) {
            reduce_ln_k<2><<<B_ * L_, 256, 0, stream>>>(
                part_h, h, ln_w + (li + 1) * DM_, ln_b + (li + 1) * DM_,
                xln_b, (size_t)B_ * L_ * DM_);
        }
    }

    // fused last-layer residual + final LN + head
    head_ln_k<<<B_ * P_, 256, 0, stream>>>(
        h, part_h, (size_t)B_ * L_ * DM_, fnorm_w, fnorm_b, head_w, out);
}